// Round 1
// baseline (47.318 us; speedup 1.0000x reference)
//
#include <hip/hip_runtime.h>

// SVR inference: out[i] = sum_j exp(-|f_i - f_j|^2 / (2*sigma^2)) * alpha[j] + bias
// N = 4096 rows, D = 64 features, sigma = 5.
//
// Round 1: fp32 vector-ALU baseline.
//  - d2 = sq_i + sq_j - 2*dot(f_i, f_j)   (64 FMA per pair instead of 128 ops)
//  - thread t holds row i's 64 features in VGPRs; F[j] is wave-uniform ->
//    scalar loads (s_load) feed one SGPR operand per v_fmac.
//  - j split into 32 chunks of 128 for occupancy; partials combined via atomicAdd.

#define NN 4096
#define DD 64
#define JCHUNK 128

__global__ __launch_bounds__(256) void svr_prep(const float* __restrict__ F,
                                                const float* __restrict__ bias,
                                                float* __restrict__ sq,
                                                float* __restrict__ out) {
    int i = blockIdx.x * 256 + threadIdx.x;
    const float4* Fr = reinterpret_cast<const float4*>(F + (size_t)i * DD);
    float s = 0.f;
#pragma unroll
    for (int d = 0; d < DD / 4; ++d) {
        float4 v = Fr[d];
        s = fmaf(v.x, v.x, s);
        s = fmaf(v.y, v.y, s);
        s = fmaf(v.z, v.z, s);
        s = fmaf(v.w, v.w, s);
    }
    sq[i] = s;
    out[i] = bias[0];   // re-initialize every call (atomics accumulate on top)
}

__global__ __launch_bounds__(256) void svr_main(const float* __restrict__ F,
                                                const float* __restrict__ alpha,
                                                const float* __restrict__ sq,
                                                float* __restrict__ out) {
    const int i = blockIdx.x * 256 + threadIdx.x;
    const int j0 = blockIdx.y * JCHUNK;

    // Own row into VGPRs (64 regs), coalesced-ish float4 loads, L2-hot.
    float fi[DD];
#pragma unroll
    for (int d = 0; d < DD / 4; ++d) {
        float4 v = reinterpret_cast<const float4*>(F + (size_t)i * DD)[d];
        fi[4 * d + 0] = v.x;
        fi[4 * d + 1] = v.y;
        fi[4 * d + 2] = v.z;
        fi[4 * d + 3] = v.w;
    }
    const float sqi = sq[i];

    constexpr float kInv = 1.0f / (2.0f * 5.0f * 5.0f);   // 1/(2*sigma^2)
    float acc = 0.f;

    for (int j = j0; j < j0 + JCHUNK; ++j) {
        const float* __restrict__ fj = F + (size_t)j * DD;   // wave-uniform -> s_load
        float p0 = 0.f, p1 = 0.f, p2 = 0.f, p3 = 0.f;        // break FMA dep chain
#pragma unroll
        for (int d = 0; d < DD; d += 4) {
            p0 = fmaf(fi[d + 0], fj[d + 0], p0);
            p1 = fmaf(fi[d + 1], fj[d + 1], p1);
            p2 = fmaf(fi[d + 2], fj[d + 2], p2);
            p3 = fmaf(fi[d + 3], fj[d + 3], p3);
        }
        const float dot = (p0 + p1) + (p2 + p3);
        float d2 = sqi + sq[j] - 2.f * dot;
        d2 = fmaxf(d2, 0.f);
        acc = fmaf(__expf(-d2 * kInv), alpha[j], acc);
    }

    atomicAdd(&out[i], acc);
}

extern "C" void kernel_launch(void* const* d_in, const int* in_sizes, int n_in,
                              void* d_out, int out_size, void* d_ws, size_t ws_size,
                              hipStream_t stream) {
    const float* F     = (const float*)d_in[0];   // [4096, 64] fp32
    const float* alpha = (const float*)d_in[1];   // [4096, 1] fp32
    const float* bias  = (const float*)d_in[2];   // [1, 1]  fp32
    float* out = (float*)d_out;                   // [4096]  fp32
    float* sq  = (float*)d_ws;                    // 16 KB scratch: |f_i|^2

    // Pass 1: row squared-norms + out = bias   (must precede atomics in pass 2)
    svr_prep<<<dim3(NN / 256), dim3(256), 0, stream>>>(F, bias, sq, out);

    // Pass 2: partial kernel-matvec over j-chunks, accumulated atomically.
    svr_main<<<dim3(NN / 256, NN / JCHUNK), dim3(256), 0, stream>>>(F, alpha, sq, out);
}